// Round 3
// baseline (261.684 us; speedup 1.0000x reference)
//
#include <hip/hip_runtime.h>
#include <stdint.h>

// Problem constants
#define B_   8
#define S_   2047
#define L_   2048      // S+1 (CLS prepended)
#define H_   256       // HIDDEN
#define NH_  8
#define HD_  32
#define V_   32001     // VOCAB+1
#define NCH_ 64        // t-chunks per b
#define TCH_ 32        // t per chunk (NCH_*TCH_ == L_)
#define GRID_ 512

__device__ __forceinline__ float b2f(unsigned short u) {
    union { uint32_t i; float f; } c; c.i = ((uint32_t)u) << 16; return c.f;
}
__device__ __forceinline__ unsigned short f2b(float f) {
    union { float f; uint32_t i; } c; c.f = f;
    uint32_t x = c.i;
    uint32_t r = (x + 0x7fffu + ((x >> 16) & 1u)) >> 16;
    return (unsigned short)r;
}
__device__ __forceinline__ float foldx(float a, int off) {
    return a + __shfl_xor(a, off, 64);
}
__device__ __forceinline__ float sel8(const float a[8], int j) {
    float v = a[0];
    v = (j == 1) ? a[1] : v;
    v = (j == 2) ? a[2] : v;
    v = (j == 3) ? a[3] : v;
    v = (j == 4) ? a[4] : v;
    v = (j == 5) ? a[5] : v;
    v = (j == 6) ? a[6] : v;
    v = (j == 7) ? a[7] : v;
    return v;
}

// ---------------------------------------------------------------------------
// Software grid barrier (graph-capture-safe; no cooperative API).
// Two-level: 16 sub-counters (bid&15) -> 1 master. Device-scope fences:
// __threadfence() on gfx950 agent scope emits buffer_wbl2 (release: XCD L2
// writeback to LLC) / buffer_inv (acquire: L1+L2 invalidate), so cross-XCD
// visibility is guaranteed. Spin load is agent-scope (LLC-direct).
// Counters live in ws, zeroed by hipMemsetAsync before launch each iter.
// Each barrier uses its own 2 KB region -> no reset hazards.
// ---------------------------------------------------------------------------
__device__ __forceinline__ void gsync(unsigned int* bp, int bid) {
    __syncthreads();                       // includes vmcnt drain of this block's stores
    if (threadIdx.x == 0) {
        __threadfence();                   // release: L2 writeback
        unsigned int* sub = bp + 16 + (bid & 15) * 16;
        unsigned int prev = atomicAdd(sub, 1u);
        if (prev == (GRID_ / 16) - 1)      // last arriver of this sub-group
            atomicAdd(bp, 1u);             // bump master
        while (__hip_atomic_load(bp, __ATOMIC_RELAXED, __HIP_MEMORY_SCOPE_AGENT) < 16u)
            __builtin_amdgcn_s_sleep(1);
        __threadfence();                   // acquire: L1+L2 invalidate
    }
    __syncthreads();
}

// ---------------------------------------------------------------------------
// Single mega kernel, phases = round-0 kernels verbatim; 5 software barriers
// replace the 5 inter-kernel launch boundaries.
//   P0 (blocks 0..7):  y0 = emb[2]+pe[0]; qk[n][h] = (wq_n y0)·wk_n / sqrt(32)
//   P1 (all, x8 stride): per-(b,t) wave: emb+pe gather -> ycache(bf16),
//                        8 score dots -> 17-shuffle fold -> E=exp -> Et
//   P2 (all, 1:1):     ybar psums per (b,chunk): psum, esum_blk
//   P3 (blocks 0..63): reduce chunks -> ybar -> wv proj -> o_g
//   P4 (blocks 0..7):  z = wo·o + 2*y0
//   P5 (blocks 0..500): out[b,v] = z·wu[v]
// __launch_bounds__(256,2): VGPR <= 256, LDS ~7.3 KB -> 2 blocks/CU ->
// all 512 blocks co-resident -> software barrier cannot deadlock.
// ---------------------------------------------------------------------------
__global__ __launch_bounds__(256, 2) void mega(const int* __restrict__ x,
                                               const float* __restrict__ emb,
                                               const float* __restrict__ wq,
                                               const float* __restrict__ wk,
                                               const float* __restrict__ wv,
                                               const float* __restrict__ wo,
                                               const float* __restrict__ wu,
                                               float* __restrict__ out,
                                               float* __restrict__ qk,
                                               float* __restrict__ y0,
                                               float* __restrict__ z,
                                               float* __restrict__ o_g,
                                               float* __restrict__ esum_blk,
                                               float* __restrict__ psum,
                                               float* __restrict__ Et,
                                               unsigned short* __restrict__ ycache,
                                               unsigned int* __restrict__ bars) {
    int bid = blockIdx.x, tid = threadIdx.x;

    __shared__ float sm_y0l[H_];
    __shared__ float sm_p8[HD_][8];      // P0 q0p, P3 op
    __shared__ float sm_v32[HD_];        // P0 q0_l
    __shared__ float sm_e[TCH_ * NH_];   // P2
    __shared__ float sm_ybar[H_];        // P3
    __shared__ float sm_inv;             // P3
    __shared__ float sm_o256[NH_ * HD_]; // P4
    __shared__ float sm_out[B_ * 65];    // P5

    // ---- P0: qk prep (8 blocks) ----
    if (bid < NH_) {
        int n = bid;
        float v = emb[2 * H_ + tid] + ((tid & 1) ? 1.0f : 0.0f);  // pe[0]
        sm_y0l[tid] = v;
        if (n == 0) y0[tid] = v;
        __syncthreads();
        {
            int k = tid >> 3, part = tid & 7;
            const float* w = wq + (n * HD_ + k) * H_ + part * 32;
            const float* yy = sm_y0l + part * 32;
            float acc = 0.f;
#pragma unroll
            for (int j = 0; j < 32; ++j) acc += w[j] * yy[j];
            sm_p8[k][part] = acc;
        }
        __syncthreads();
        if (tid < HD_) {
            float s = 0.f;
#pragma unroll
            for (int j = 0; j < 8; ++j) s += sm_p8[tid][j];
            sm_v32[tid] = s;
        }
        __syncthreads();
        float acc = 0.f;
        for (int k = 0; k < HD_; ++k)
            acc += sm_v32[k] * wk[(n * HD_ + k) * H_ + tid];
        qk[n * H_ + tid] = acc * 0.17677669529663687f;  // 1/sqrt(32)
    }
    gsync(bars + 0 * 512, bid);

    // ---- P1: scores + ycache (grid-stride x8 over 4096 virtual blocks) ----
    {
        int lane = tid & 63;
        int h0 = lane * 4;
        float4 qr[NH_];
#pragma unroll
        for (int n = 0; n < NH_; ++n)
            qr[n] = *(const float4*)(qk + n * H_ + h0);

        const float cdiv = 0.07195578414202881f;  // ln(10000)/128
        float div0 = __expf(-(float)(lane * 2) * cdiv);
        float div1 = __expf(-(float)(lane * 2 + 1) * cdiv);

        for (int g = bid; g < 4096; g += GRID_) {
            int gid = g * 4 + (tid >> 6);   // (b,t) flat: 0..16383
            int b = gid >> 11, t = gid & (L_ - 1);

            float a0 = (float)t * div0, a1 = (float)t * div1;
            float s0 = __sinf(a0), c0 = __cosf(a0);
            float s1 = __sinf(a1), c1 = __cosf(a1);

            int tok = (t == 0) ? 2 : x[b * S_ + t - 1];
            float4 ev = *(const float4*)(emb + (size_t)tok * H_ + h0);
            float4 y4;
            y4.x = ev.x + s0; y4.y = ev.y + c0; y4.z = ev.z + s1; y4.w = ev.w + c1;
            ushort4 st;
            st.x = f2b(y4.x); st.y = f2b(y4.y); st.z = f2b(y4.z); st.w = f2b(y4.w);
            *(ushort4*)(ycache + ((size_t)gid << 8) + h0) = st;

            float a[NH_];
#pragma unroll
            for (int n = 0; n < NH_; ++n)
                a[n] = qr[n].x * y4.x + qr[n].y * y4.y + qr[n].z * y4.z + qr[n].w * y4.w;
            float m4[4];
#pragma unroll
            for (int k = 0; k < 4; ++k) {
                float lo = foldx(a[k], 32), hi = foldx(a[k + 4], 32);
                m4[k] = (lane & 32) ? hi : lo;
            }
            float m2[2];
#pragma unroll
            for (int k = 0; k < 2; ++k) {
                float lo = foldx(m4[k], 16), hi = foldx(m4[k + 2], 16);
                m2[k] = (lane & 16) ? hi : lo;
            }
            float lo = foldx(m2[0], 8), hi = foldx(m2[1], 8);
            float m1 = (lane & 8) ? hi : lo;
            m1 = foldx(m1, 4); m1 = foldx(m1, 2); m1 = foldx(m1, 1);
            float e = __expf(m1);
            if ((lane & 7) == 0)
                Et[(size_t)gid * NH_ + (lane >> 3)] = e;
        }
    }
    gsync(bars + 1 * 512, bid);

    // ---- P2: ybar partial sums (512 blocks, 1:1) ----
    {
        int b = bid >> 6, c = bid & 63;
        int t0 = c * TCH_;

        sm_e[tid] = Et[(size_t)(b * L_ + t0) * NH_ + tid];
        __syncthreads();
        if (tid < NH_) {
            float s = 0.f;
#pragma unroll
            for (int tt = 0; tt < TCH_; ++tt) s += sm_e[tt * NH_ + tid];
            esum_blk[bid * NH_ + tid] = s;
        }

        float acc[NH_] = {};
        const unsigned short* yb = ycache + ((size_t)(b * L_ + t0) << 8) + tid;
#pragma unroll
        for (int tt = 0; tt < TCH_; ++tt) {
            float yv = b2f(yb[(size_t)tt << 8]);
            float4 eA = *(const float4*)&sm_e[tt * NH_];
            float4 eB = *(const float4*)&sm_e[tt * NH_ + 4];
            acc[0] += eA.x * yv; acc[1] += eA.y * yv;
            acc[2] += eA.z * yv; acc[3] += eA.w * yv;
            acc[4] += eB.x * yv; acc[5] += eB.y * yv;
            acc[6] += eB.z * yv; acc[7] += eB.w * yv;
        }
#pragma unroll
        for (int n = 0; n < NH_; ++n)
            psum[((size_t)bid * NH_ + n) * H_ + tid] = acc[n];
    }
    gsync(bars + 2 * 512, bid);

    // ---- P3: head reduce + wv projection (64 blocks) ----
    if (bid < 64) {
        int b = bid >> 3, n = bid & 7;
        if (tid < 64) {
            float v = esum_blk[(b * NCH_ + tid) * NH_ + n];
#pragma unroll
            for (int off = 32; off > 0; off >>= 1) v += __shfl_xor(v, off, 64);
            if (tid == 0) sm_inv = 1.0f / v;
        }
        __syncthreads();
        {
            const float* pp = psum + ((size_t)(b * NCH_) * NH_ + n) * H_ + tid;
            float s = 0.f;
#pragma unroll 8
            for (int cc = 0; cc < NCH_; ++cc) s += pp[(size_t)cc * NH_ * H_];
            sm_ybar[tid] = s * sm_inv;
        }
        __syncthreads();
        {
            int k = tid >> 3, p = tid & 7;
            const float* wrow = wv + (size_t)(n * HD_ + k) * H_ + p * 32;
            const float* yy = sm_ybar + p * 32;
            float s = 0.f;
#pragma unroll
            for (int j = 0; j < 32; ++j) s += wrow[j] * yy[j];
            sm_p8[k][p] = s;
        }
        __syncthreads();
        if (tid < HD_) {
            float s = 0.f;
#pragma unroll
            for (int p = 0; p < 8; ++p) s += sm_p8[tid][p];
            o_g[b * (NH_ * HD_) + n * HD_ + tid] = s;
        }
    }
    gsync(bars + 3 * 512, bid);

    // ---- P4: z = wo·o + 2*y0 (8 blocks) ----
    if (bid < B_) {
        int b = bid;
        sm_o256[tid] = o_g[b * (NH_ * HD_) + tid];
        __syncthreads();
        const float* wrow = wo + (size_t)tid * (NH_ * HD_);
        float s = 0.f;
#pragma unroll 16
        for (int j4 = 0; j4 < (NH_ * HD_) / 4; ++j4) {
            float4 w4 = *(const float4*)(wrow + j4 * 4);
            s += w4.x * sm_o256[j4 * 4] + w4.y * sm_o256[j4 * 4 + 1]
               + w4.z * sm_o256[j4 * 4 + 2] + w4.w * sm_o256[j4 * 4 + 3];
        }
        z[b * H_ + tid] = s + 2.0f * y0[tid];
    }
    gsync(bars + 4 * 512, bid);

    // ---- P5: out = z · wu^T (501 blocks) ----
    if (bid < (V_ + 63) / 64) {
        int lane = tid & 63, w = tid >> 6;
        int m = lane & 15;
        int g = lane >> 4;
        int hb = m * 16;
        float zr[B_][16];
#pragma unroll
        for (int b = 0; b < B_; ++b)
#pragma unroll
            for (int jj = 0; jj < 4; ++jj)
                *(float4*)&zr[b][jj * 4] = *(const float4*)(z + b * H_ + hb + jj * 4);

        int base = bid * 64;
#pragma unroll
        for (int pass = 0; pass < 4; ++pass) {
            int rl = w * 16 + pass * 4 + g;
            int v = base + rl;
            int vc = (v < V_) ? v : (V_ - 1);
            const float* wr = wu + (size_t)vc * H_ + hb;
            float4 w0 = *(const float4*)(wr);
            float4 w1 = *(const float4*)(wr + 4);
            float4 w2 = *(const float4*)(wr + 8);
            float4 w3 = *(const float4*)(wr + 12);
            float acc[B_];
#pragma unroll
            for (int b = 0; b < B_; ++b) {
                acc[b] = zr[b][0] * w0.x + zr[b][1] * w0.y + zr[b][2] * w0.z + zr[b][3] * w0.w
                       + zr[b][4] * w1.x + zr[b][5] * w1.y + zr[b][6] * w1.z + zr[b][7] * w1.w
                       + zr[b][8] * w2.x + zr[b][9] * w2.y + zr[b][10] * w2.z + zr[b][11] * w2.w
                       + zr[b][12] * w3.x + zr[b][13] * w3.y + zr[b][14] * w3.z + zr[b][15] * w3.w;
            }
#pragma unroll
            for (int off = 1; off <= 8; off <<= 1) {
#pragma unroll
                for (int b = 0; b < B_; ++b) acc[b] += __shfl_xor(acc[b], off, 64);
            }
            if (m < B_) sm_out[m * 65 + rl] = sel8(acc, m);
        }
        __syncthreads();
        for (int i = tid; i < B_ * 64; i += 256) {
            int b = i >> 6, vl = i & 63, v = base + vl;
            if (v < V_) out[b * V_ + v] = sm_out[b * 65 + vl];
        }
    }
}

// ---------------------------------------------------------------------------
extern "C" void kernel_launch(void* const* d_in, const int* in_sizes, int n_in,
                              void* d_out, int out_size, void* d_ws, size_t ws_size,
                              hipStream_t stream) {
    const int*   x   = (const int*)d_in[0];
    const float* emb = (const float*)d_in[1];
    const float* wq  = (const float*)d_in[2];
    const float* wk  = (const float*)d_in[3];
    const float* wv  = (const float*)d_in[4];
    const float* wo  = (const float*)d_in[5];
    const float* wu  = (const float*)d_in[6];
    float*       out = (float*)d_out;

    // ws layout (floats unless noted), ~13 MiB total:
    // qk[2048] | y0[256] | z[2048] | o_g[2048] | esum_blk[4096]
    // | psum[512*8*256] | Et[16384*8] | ycache[16384*256 ushort] | bars[5*512 u32]
    float* qk       = (float*)d_ws;
    float* y0       = qk + NH_ * H_;
    float* z        = y0 + H_;
    float* o_g      = z + B_ * H_;
    float* esum_blk = o_g + NH_ * HD_ * B_;
    float* psum     = esum_blk + 512 * NH_;
    float* Et       = psum + (size_t)512 * NH_ * H_;
    unsigned short* ycache = (unsigned short*)(Et + (size_t)B_ * L_ * NH_);
    unsigned int*   bars   = (unsigned int*)(ycache + (size_t)B_ * L_ * H_);

    // Zero the barrier counters (workspace is poisoned each iteration).
    hipMemsetAsync(bars, 0, 5 * 512 * sizeof(unsigned int), stream);

    mega<<<GRID_, 256, 0, stream>>>(x, emb, wq, wk, wv, wo, wu, out,
                                    qk, y0, z, o_g, esum_blk, psum, Et, ycache, bars);
}

// Round 4
// 233.815 us; speedup vs baseline: 1.1192x; 1.1192x over previous
//
#include <hip/hip_runtime.h>
#include <stdint.h>

// Problem constants
#define B_   8
#define S_   2047
#define L_   2048      // S+1 (CLS prepended)
#define H_   256       // HIDDEN
#define NH_  8
#define HD_  32
#define V_   32001     // VOCAB+1
#define NCH_ 64        // t-chunks per b
#define TCH_ 32        // t per chunk (NCH_*TCH_ == L_)
#define GRID_ 512
#define BAR_STRIDE_ 2048   // u32 per barrier region (8 KB)

__device__ __forceinline__ float b2f(unsigned short u) {
    union { uint32_t i; float f; } c; c.i = ((uint32_t)u) << 16; return c.f;
}
__device__ __forceinline__ unsigned short f2b(float f) {
    union { float f; uint32_t i; } c; c.f = f;
    uint32_t x = c.i;
    uint32_t r = (x + 0x7fffu + ((x >> 16) & 1u)) >> 16;
    return (unsigned short)r;
}
__device__ __forceinline__ float foldx(float a, int off) {
    return a + __shfl_xor(a, off, 64);
}
__device__ __forceinline__ float sel8(const float a[8], int j) {
    float v = a[0];
    v = (j == 1) ? a[1] : v;
    v = (j == 2) ? a[2] : v;
    v = (j == 3) ? a[3] : v;
    v = (j == 4) ? a[4] : v;
    v = (j == 5) ? a[5] : v;
    v = (j == 6) ? a[6] : v;
    v = (j == 7) ? a[7] : v;
    return v;
}

// ---------------------------------------------------------------------------
// Software grid barrier, contention-free layout (fix for round-3's 150 µs
// spin congestion: 512 pollers hammered ONE LLC line, starving the release
// atomics). New design:
//   arrival: 32 sub-counters (64 B apart, 16 blocks each)  — no pollers
//   master:  touched by exactly 32 sub-leaders              — no pollers
//   release: 32 separate flag lines, written by final arriver;
//            each block polls only its own line (16 pollers/line) with
//            s_sleep(8) (~0.5 us) -> ~1 access/70cyc/line. No queueing.
// Fences: __threadfence release before arrival (L2 wb to LLC), acquire
// after release detect (L1/L2 inv) -> cross-XCD visibility.
// Region layout (u32): [0]=master | [16+i*16]=sub_i | [528+i*16]=rel_i.
// Zeroed by hipMemsetAsync each launch (workspace is poisoned).
// ---------------------------------------------------------------------------
__device__ __forceinline__ void gsync(unsigned int* bp, int bid) {
    __syncthreads();
    if (threadIdx.x == 0) {
        int sg = bid & 31;                           // 32 subgroups x 16 blocks
        unsigned int* sub = bp + 16 + sg * 16;
        unsigned int* rel = bp + 528 + sg * 16;
        __threadfence();                             // release: wb to LLC
        unsigned int prev = __hip_atomic_fetch_add(sub, 1u, __ATOMIC_RELAXED,
                                                   __HIP_MEMORY_SCOPE_AGENT);
        if (prev == 15u) {                           // last of subgroup
            unsigned int m = __hip_atomic_fetch_add(bp, 1u, __ATOMIC_RELAXED,
                                                    __HIP_MEMORY_SCOPE_AGENT);
            if (m == 31u) {                          // final arriver: broadcast
                for (int i = 0; i < 32; ++i)
                    __hip_atomic_store(bp + 528 + i * 16, 1u, __ATOMIC_RELAXED,
                                       __HIP_MEMORY_SCOPE_AGENT);
            }
        }
        while (__hip_atomic_load(rel, __ATOMIC_RELAXED,
                                 __HIP_MEMORY_SCOPE_AGENT) == 0u)
            __builtin_amdgcn_s_sleep(8);
        __threadfence();                             // acquire: inv L1/L2
    }
    __syncthreads();
}

// ---------------------------------------------------------------------------
// Single mega kernel, phases = round-0 kernels verbatim; 5 software barriers
// replace the 5 inter-kernel launch boundaries.
//   P0 (blocks 0..7):  y0 = emb[2]+pe[0]; qk[n][h] = (wq_n y0)·wk_n / sqrt(32)
//   P1 (all, x8 stride): per-(b,t) wave: emb+pe gather -> ycache(bf16),
//                        8 score dots -> 17-shuffle fold -> E=exp -> Et
//   P2 (all, 1:1):     ybar psums per (b,chunk): psum, esum_blk
//   P3 (blocks 0..63): reduce chunks -> ybar -> wv proj -> o_g
//   P4 (blocks 0..7):  z = wo·o + 2*y0
//   P5 (blocks 0..500): out[b,v] = z·wu[v]
// __launch_bounds__(256,2): VGPR <= 256, LDS ~15.5 KB -> 2 blocks/CU ->
// all 512 blocks co-resident -> software barrier cannot deadlock.
// ---------------------------------------------------------------------------
__global__ __launch_bounds__(256, 2) void mega(const int* __restrict__ x,
                                               const float* __restrict__ emb,
                                               const float* __restrict__ wq,
                                               const float* __restrict__ wk,
                                               const float* __restrict__ wv,
                                               const float* __restrict__ wo,
                                               const float* __restrict__ wu,
                                               float* __restrict__ out,
                                               float* __restrict__ qk,
                                               float* __restrict__ y0,
                                               float* __restrict__ z,
                                               float* __restrict__ o_g,
                                               float* __restrict__ esum_blk,
                                               float* __restrict__ psum,
                                               float* __restrict__ Et,
                                               unsigned short* __restrict__ ycache,
                                               unsigned int* __restrict__ bars) {
    int bid = blockIdx.x, tid = threadIdx.x;

    __shared__ float sm_y0l[H_];
    __shared__ float sm_p8[HD_][8];      // P0 q0p, P3 op
    __shared__ float sm_v32[HD_];        // P0 q0_l
    __shared__ float sm_e[TCH_ * NH_];   // P2
    __shared__ float sm_ybar[H_];        // P3
    __shared__ float sm_inv;             // P3
    __shared__ float sm_o256[NH_ * HD_]; // P4
    __shared__ float sm_out[B_ * 65];    // P5

    // ---- P0: qk prep (8 blocks) ----
    if (bid < NH_) {
        int n = bid;
        float v = emb[2 * H_ + tid] + ((tid & 1) ? 1.0f : 0.0f);  // pe[0]
        sm_y0l[tid] = v;
        if (n == 0) y0[tid] = v;
        __syncthreads();
        {
            int k = tid >> 3, part = tid & 7;
            const float* w = wq + (n * HD_ + k) * H_ + part * 32;
            const float* yy = sm_y0l + part * 32;
            float acc = 0.f;
#pragma unroll
            for (int j = 0; j < 32; ++j) acc += w[j] * yy[j];
            sm_p8[k][part] = acc;
        }
        __syncthreads();
        if (tid < HD_) {
            float s = 0.f;
#pragma unroll
            for (int j = 0; j < 8; ++j) s += sm_p8[tid][j];
            sm_v32[tid] = s;
        }
        __syncthreads();
        float acc = 0.f;
        for (int k = 0; k < HD_; ++k)
            acc += sm_v32[k] * wk[(n * HD_ + k) * H_ + tid];
        qk[n * H_ + tid] = acc * 0.17677669529663687f;  // 1/sqrt(32)
    }
    gsync(bars + 0 * BAR_STRIDE_, bid);

    // ---- P1: scores + ycache (grid-stride x8 over 4096 virtual blocks) ----
    {
        int lane = tid & 63;
        int h0 = lane * 4;
        float4 qr[NH_];
#pragma unroll
        for (int n = 0; n < NH_; ++n)
            qr[n] = *(const float4*)(qk + n * H_ + h0);

        const float cdiv = 0.07195578414202881f;  // ln(10000)/128
        float div0 = __expf(-(float)(lane * 2) * cdiv);
        float div1 = __expf(-(float)(lane * 2 + 1) * cdiv);

        for (int g = bid; g < 4096; g += GRID_) {
            int gid = g * 4 + (tid >> 6);   // (b,t) flat: 0..16383
            int b = gid >> 11, t = gid & (L_ - 1);

            float a0 = (float)t * div0, a1 = (float)t * div1;
            float s0 = __sinf(a0), c0 = __cosf(a0);
            float s1 = __sinf(a1), c1 = __cosf(a1);

            int tok = (t == 0) ? 2 : x[b * S_ + t - 1];
            float4 ev = *(const float4*)(emb + (size_t)tok * H_ + h0);
            float4 y4;
            y4.x = ev.x + s0; y4.y = ev.y + c0; y4.z = ev.z + s1; y4.w = ev.w + c1;
            ushort4 st;
            st.x = f2b(y4.x); st.y = f2b(y4.y); st.z = f2b(y4.z); st.w = f2b(y4.w);
            *(ushort4*)(ycache + ((size_t)gid << 8) + h0) = st;

            float a[NH_];
#pragma unroll
            for (int n = 0; n < NH_; ++n)
                a[n] = qr[n].x * y4.x + qr[n].y * y4.y + qr[n].z * y4.z + qr[n].w * y4.w;
            float m4[4];
#pragma unroll
            for (int k = 0; k < 4; ++k) {
                float lo = foldx(a[k], 32), hi = foldx(a[k + 4], 32);
                m4[k] = (lane & 32) ? hi : lo;
            }
            float m2[2];
#pragma unroll
            for (int k = 0; k < 2; ++k) {
                float lo = foldx(m4[k], 16), hi = foldx(m4[k + 2], 16);
                m2[k] = (lane & 16) ? hi : lo;
            }
            float lo = foldx(m2[0], 8), hi = foldx(m2[1], 8);
            float m1 = (lane & 8) ? hi : lo;
            m1 = foldx(m1, 4); m1 = foldx(m1, 2); m1 = foldx(m1, 1);
            float e = __expf(m1);
            if ((lane & 7) == 0)
                Et[(size_t)gid * NH_ + (lane >> 3)] = e;
        }
    }
    gsync(bars + 1 * BAR_STRIDE_, bid);

    // ---- P2: ybar partial sums (512 blocks, 1:1) ----
    {
        int b = bid >> 6, c = bid & 63;
        int t0 = c * TCH_;

        sm_e[tid] = Et[(size_t)(b * L_ + t0) * NH_ + tid];
        __syncthreads();
        if (tid < NH_) {
            float s = 0.f;
#pragma unroll
            for (int tt = 0; tt < TCH_; ++tt) s += sm_e[tt * NH_ + tid];
            esum_blk[bid * NH_ + tid] = s;
        }

        float acc[NH_] = {};
        const unsigned short* yb = ycache + ((size_t)(b * L_ + t0) << 8) + tid;
#pragma unroll
        for (int tt = 0; tt < TCH_; ++tt) {
            float yv = b2f(yb[(size_t)tt << 8]);
            float4 eA = *(const float4*)&sm_e[tt * NH_];
            float4 eB = *(const float4*)&sm_e[tt * NH_ + 4];
            acc[0] += eA.x * yv; acc[1] += eA.y * yv;
            acc[2] += eA.z * yv; acc[3] += eA.w * yv;
            acc[4] += eB.x * yv; acc[5] += eB.y * yv;
            acc[6] += eB.z * yv; acc[7] += eB.w * yv;
        }
#pragma unroll
        for (int n = 0; n < NH_; ++n)
            psum[((size_t)bid * NH_ + n) * H_ + tid] = acc[n];
    }
    gsync(bars + 2 * BAR_STRIDE_, bid);

    // ---- P3: head reduce + wv projection (64 blocks) ----
    if (bid < 64) {
        int b = bid >> 3, n = bid & 7;
        if (tid < 64) {
            float v = esum_blk[(b * NCH_ + tid) * NH_ + n];
#pragma unroll
            for (int off = 32; off > 0; off >>= 1) v += __shfl_xor(v, off, 64);
            if (tid == 0) sm_inv = 1.0f / v;
        }
        __syncthreads();
        {
            const float* pp = psum + ((size_t)(b * NCH_) * NH_ + n) * H_ + tid;
            float s = 0.f;
#pragma unroll 8
            for (int cc = 0; cc < NCH_; ++cc) s += pp[(size_t)cc * NH_ * H_];
            sm_ybar[tid] = s * sm_inv;
        }
        __syncthreads();
        {
            int k = tid >> 3, p = tid & 7;
            const float* wrow = wv + (size_t)(n * HD_ + k) * H_ + p * 32;
            const float* yy = sm_ybar + p * 32;
            float s = 0.f;
#pragma unroll
            for (int j = 0; j < 32; ++j) s += wrow[j] * yy[j];
            sm_p8[k][p] = s;
        }
        __syncthreads();
        if (tid < HD_) {
            float s = 0.f;
#pragma unroll
            for (int p = 0; p < 8; ++p) s += sm_p8[tid][p];
            o_g[b * (NH_ * HD_) + n * HD_ + tid] = s;
        }
    }
    gsync(bars + 3 * BAR_STRIDE_, bid);

    // ---- P4: z = wo·o + 2*y0 (8 blocks) ----
    if (bid < B_) {
        int b = bid;
        sm_o256[tid] = o_g[b * (NH_ * HD_) + tid];
        __syncthreads();
        const float* wrow = wo + (size_t)tid * (NH_ * HD_);
        float s = 0.f;
#pragma unroll 16
        for (int j4 = 0; j4 < (NH_ * HD_) / 4; ++j4) {
            float4 w4 = *(const float4*)(wrow + j4 * 4);
            s += w4.x * sm_o256[j4 * 4] + w4.y * sm_o256[j4 * 4 + 1]
               + w4.z * sm_o256[j4 * 4 + 2] + w4.w * sm_o256[j4 * 4 + 3];
        }
        z[b * H_ + tid] = s + 2.0f * y0[tid];
    }
    gsync(bars + 4 * BAR_STRIDE_, bid);

    // ---- P5: out = z · wu^T (501 blocks) ----
    if (bid < (V_ + 63) / 64) {
        int lane = tid & 63, w = tid >> 6;
        int m = lane & 15;
        int g = lane >> 4;
        int hb = m * 16;
        float zr[B_][16];
#pragma unroll
        for (int b = 0; b < B_; ++b)
#pragma unroll
            for (int jj = 0; jj < 4; ++jj)
                *(float4*)&zr[b][jj * 4] = *(const float4*)(z + b * H_ + hb + jj * 4);

        int base = bid * 64;
#pragma unroll
        for (int pass = 0; pass < 4; ++pass) {
            int rl = w * 16 + pass * 4 + g;
            int v = base + rl;
            int vc = (v < V_) ? v : (V_ - 1);
            const float* wr = wu + (size_t)vc * H_ + hb;
            float4 w0 = *(const float4*)(wr);
            float4 w1 = *(const float4*)(wr + 4);
            float4 w2 = *(const float4*)(wr + 8);
            float4 w3 = *(const float4*)(wr + 12);
            float acc[B_];
#pragma unroll
            for (int b = 0; b < B_; ++b) {
                acc[b] = zr[b][0] * w0.x + zr[b][1] * w0.y + zr[b][2] * w0.z + zr[b][3] * w0.w
                       + zr[b][4] * w1.x + zr[b][5] * w1.y + zr[b][6] * w1.z + zr[b][7] * w1.w
                       + zr[b][8] * w2.x + zr[b][9] * w2.y + zr[b][10] * w2.z + zr[b][11] * w2.w
                       + zr[b][12] * w3.x + zr[b][13] * w3.y + zr[b][14] * w3.z + zr[b][15] * w3.w;
            }
#pragma unroll
            for (int off = 1; off <= 8; off <<= 1) {
#pragma unroll
                for (int b = 0; b < B_; ++b) acc[b] += __shfl_xor(acc[b], off, 64);
            }
            if (m < B_) sm_out[m * 65 + rl] = sel8(acc, m);
        }
        __syncthreads();
        for (int i = tid; i < B_ * 64; i += 256) {
            int b = i >> 6, vl = i & 63, v = base + vl;
            if (v < V_) out[b * V_ + v] = sm_out[b * 65 + vl];
        }
    }
}

// ---------------------------------------------------------------------------
extern "C" void kernel_launch(void* const* d_in, const int* in_sizes, int n_in,
                              void* d_out, int out_size, void* d_ws, size_t ws_size,
                              hipStream_t stream) {
    const int*   x   = (const int*)d_in[0];
    const float* emb = (const float*)d_in[1];
    const float* wq  = (const float*)d_in[2];
    const float* wk  = (const float*)d_in[3];
    const float* wv  = (const float*)d_in[4];
    const float* wo  = (const float*)d_in[5];
    const float* wu  = (const float*)d_in[6];
    float*       out = (float*)d_out;

    // ws layout (floats unless noted), ~13 MiB total:
    // qk[2048] | y0[256] | z[2048] | o_g[2048] | esum_blk[4096]
    // | psum[512*8*256] | Et[16384*8] | ycache[16384*256 ushort]
    // | bars[5*2048 u32]
    float* qk       = (float*)d_ws;
    float* y0       = qk + NH_ * H_;
    float* z        = y0 + H_;
    float* o_g      = z + B_ * H_;
    float* esum_blk = o_g + NH_ * HD_ * B_;
    float* psum     = esum_blk + 512 * NH_;
    float* Et       = psum + (size_t)512 * NH_ * H_;
    unsigned short* ycache = (unsigned short*)(Et + (size_t)B_ * L_ * NH_);
    unsigned int*   bars   = (unsigned int*)(ycache + (size_t)B_ * L_ * H_);

    // Zero the barrier counters (workspace is poisoned each iteration).
    hipMemsetAsync(bars, 0, 5 * BAR_STRIDE_ * sizeof(unsigned int), stream);

    mega<<<GRID_, 256, 0, stream>>>(x, emb, wq, wk, wv, wo, wu, out,
                                    qk, y0, z, o_g, esum_blk, psum, Et, ycache, bars);
}

// Round 5
// 200.457 us; speedup vs baseline: 1.3054x; 1.1664x over previous
//
#include <hip/hip_runtime.h>
#include <stdint.h>

// Problem constants
#define B_   8
#define S_   2047
#define L_   2048      // S+1 (CLS prepended)
#define H_   256       // HIDDEN
#define NH_  8
#define HD_  32
#define V_   32001     // VOCAB+1
#define NCH_ 64        // t-chunks per b
#define TCH_ 32        // t per chunk (NCH_*TCH_ == L_)
#define GRID_ 512
#define BAR_STRIDE_ 2048   // u32 per barrier region (8 KB)

// ---------------------------------------------------------------------------
// LLC-direct (coherent) scalar access: relaxed agent-scope atomics compile to
// global_load/store with sc0 sc1 on gfx950 -> bypass L1 + XCD-L2, hit LLC.
// This replaces __threadfence-based coherence entirely (no cache-wide ops).
// ---------------------------------------------------------------------------
__device__ __forceinline__ void ast(float* p, float v) {
    __hip_atomic_store((unsigned int*)p, __float_as_uint(v),
                       __ATOMIC_RELAXED, __HIP_MEMORY_SCOPE_AGENT);
}
__device__ __forceinline__ float ald(const float* p) {
    return __uint_as_float(__hip_atomic_load((const unsigned int*)p,
                           __ATOMIC_RELAXED, __HIP_MEMORY_SCOPE_AGENT));
}
__device__ __forceinline__ float foldx(float a, int off) {
    return a + __shfl_xor(a, off, 64);
}
__device__ __forceinline__ float sel8(const float a[8], int j) {
    float v = a[0];
    v = (j == 1) ? a[1] : v;
    v = (j == 2) ? a[2] : v;
    v = (j == 3) ? a[3] : v;
    v = (j == 4) ? a[4] : v;
    v = (j == 5) ? a[5] : v;
    v = (j == 6) ? a[6] : v;
    v = (j == 7) ? a[7] : v;
    return v;
}

// ---------------------------------------------------------------------------
// Software grid barrier, FENCE-FREE. Data ordering contract:
//   producer: data via ast() -> __syncthreads() (vmcnt(0) drain: stores acked
//             at LLC) -> arrival atomicAdd
//   consumer: sees release flag (LLC) -> __syncthreads -> reads via ald()
//             (LLC-direct, stale L1/L2 irrelevant)
// Layout per region (u32): [0]=master | [16+i*16]=sub_i | [528+i*16]=rel_i.
// 32 subgroups x 16 blocks; pollers only on their own rel line.
// ---------------------------------------------------------------------------
__device__ __forceinline__ void gsync(unsigned int* bp, int bid) {
    __syncthreads();
    if (threadIdx.x == 0) {
        int sg = bid & 31;
        unsigned int* sub = bp + 16 + sg * 16;
        unsigned int* rel = bp + 528 + sg * 16;
        unsigned int prev = __hip_atomic_fetch_add(sub, 1u, __ATOMIC_RELAXED,
                                                   __HIP_MEMORY_SCOPE_AGENT);
        if (prev == 15u) {
            unsigned int m = __hip_atomic_fetch_add(bp, 1u, __ATOMIC_RELAXED,
                                                    __HIP_MEMORY_SCOPE_AGENT);
            if (m == 31u) {
                for (int i = 0; i < 32; ++i)
                    __hip_atomic_store(bp + 528 + i * 16, 1u, __ATOMIC_RELAXED,
                                       __HIP_MEMORY_SCOPE_AGENT);
            }
        }
        while (__hip_atomic_load(rel, __ATOMIC_RELAXED,
                                 __HIP_MEMORY_SCOPE_AGENT) == 0u)
            __builtin_amdgcn_s_sleep(2);
    }
    __syncthreads();
}

// ---------------------------------------------------------------------------
// Mega kernel, 4 phases, 3 barriers:
//   P0 (blocks 0..7):  qk[n][h] = (wq_n y0)·wk_n / sqrt(32)        -> qk (LLC)
//   A  (all 512, 1:1 chunk): fused scores+ybar (round-1 kB body):
//        per (b,t): y = emb+pe in fp32 regs; 8 score dots -> fold -> e;
//        acc[n] += e_n*y. Cross-wave LDS reduce -> psum, esum (LLC)
//   B  (blocks 0..7, per b): esum+psum reduce -> ybar -> wv -> wo
//        -> z = wo·o + 2*y0 (LLC)
//   C  (blocks 0..500): out[b,v] = z·wu[v]
// LDS ~41 KB -> 2 blocks/CU -> all 512 co-resident (proven rounds 3/4).
// ---------------------------------------------------------------------------
__global__ __launch_bounds__(256, 2) void mega(const int* __restrict__ x,
                                               const float* __restrict__ emb,
                                               const float* __restrict__ wq,
                                               const float* __restrict__ wk,
                                               const float* __restrict__ wv,
                                               const float* __restrict__ wo,
                                               const float* __restrict__ wu,
                                               float* __restrict__ out,
                                               float* __restrict__ qk,
                                               float* __restrict__ z,
                                               float* __restrict__ esum_blk,
                                               float* __restrict__ psum,
                                               unsigned int* __restrict__ bars) {
    int bid = blockIdx.x, tid = threadIdx.x;

    __shared__ float smem_big[4][2056];  // A: red[w][2048] + es[w][8] @2048
    __shared__ float smem_q[NH_ * H_];   // A: qk_l; B: ybar; (8 KB)

    // ---- P0: qk prep (8 blocks) ----
    if (bid < NH_) {
        int n = bid;
        float* y0l = smem_big[3];
        float* q0p = smem_big[1];   // [k*8+part]
        float* q0l = smem_big[2];
        float v = emb[2 * H_ + tid] + ((tid & 1) ? 1.0f : 0.0f);  // pe[0]
        y0l[tid] = v;
        __syncthreads();
        {
            int k = tid >> 3, part = tid & 7;
            const float* w = wq + (n * HD_ + k) * H_ + part * 32;
            const float* yy = y0l + part * 32;
            float acc = 0.f;
#pragma unroll
            for (int j = 0; j < 32; ++j) acc += w[j] * yy[j];
            q0p[k * 8 + part] = acc;
        }
        __syncthreads();
        if (tid < HD_) {
            float s = 0.f;
#pragma unroll
            for (int j = 0; j < 8; ++j) s += q0p[tid * 8 + j];
            q0l[tid] = s;
        }
        __syncthreads();
        float acc = 0.f;
        for (int k = 0; k < HD_; ++k)
            acc += q0l[k] * wk[(n * HD_ + k) * H_ + tid];
        ast(qk + n * H_ + tid, acc * 0.17677669529663687f);  // 1/sqrt(32)
    }
    gsync(bars + 0 * BAR_STRIDE_, bid);

    // ---- A: fused scores + ybar psums (512 blocks, 1:1 chunk) ----
    {
        int b = bid >> 6, c = bid & 63;
        int lane = tid & 63, w = tid >> 6;
        int h0 = lane * 4;

        for (int i = tid; i < NH_ * H_; i += 256)
            smem_q[i] = ald(qk + i);
        __syncthreads();

        float4 qr[NH_];
#pragma unroll
        for (int n = 0; n < NH_; ++n)
            qr[n] = *(const float4*)&smem_q[n * H_ + h0];

        const float cdiv = 0.07195578414202881f;  // ln(10000)/128
        float div0 = __expf(-(float)(lane * 2) * cdiv);
        float div1 = __expf(-(float)(lane * 2 + 1) * cdiv);

        float4 acc[NH_];
        float es[NH_];
#pragma unroll
        for (int n = 0; n < NH_; ++n) {
            acc[n] = make_float4(0.f, 0.f, 0.f, 0.f);
            es[n] = 0.f;
        }

        int t0 = c * TCH_ + w * 8;
        int toks[8];
#pragma unroll
        for (int i = 0; i < 8; ++i) {
            int t = t0 + i;
            toks[i] = (t == 0) ? 2 : x[b * S_ + t - 1];
        }

#pragma unroll
        for (int i = 0; i < 8; ++i) {
            int t = t0 + i;
            float4 ev = *(const float4*)(emb + (size_t)toks[i] * H_ + h0);
            float a0 = (float)t * div0, a1 = (float)t * div1;
            float4 y4;
            y4.x = ev.x + __sinf(a0); y4.y = ev.y + __cosf(a0);
            y4.z = ev.z + __sinf(a1); y4.w = ev.w + __cosf(a1);

            float a[NH_];
#pragma unroll
            for (int n = 0; n < NH_; ++n)
                a[n] = qr[n].x * y4.x + qr[n].y * y4.y + qr[n].z * y4.z + qr[n].w * y4.w;

            float m4[4];
#pragma unroll
            for (int k = 0; k < 4; ++k) {
                float lo = foldx(a[k], 32), hi = foldx(a[k + 4], 32);
                m4[k] = (lane & 32) ? hi : lo;
            }
            float m2[2];
#pragma unroll
            for (int k = 0; k < 2; ++k) {
                float lo = foldx(m4[k], 16), hi = foldx(m4[k + 2], 16);
                m2[k] = (lane & 16) ? hi : lo;
            }
            float lo = foldx(m2[0], 8), hi = foldx(m2[1], 8);
            float m1 = (lane & 8) ? hi : lo;
            m1 = foldx(m1, 4); m1 = foldx(m1, 2); m1 = foldx(m1, 1);
            float e = __expf(m1);  // lane n*8.. holds head n's score sum

#pragma unroll
            for (int n = 0; n < NH_; ++n) {
                float en = __shfl(e, n * 8, 64);
                acc[n].x += en * y4.x; acc[n].y += en * y4.y;
                acc[n].z += en * y4.z; acc[n].w += en * y4.w;
                es[n] += en;
            }
        }

#pragma unroll
        for (int n = 0; n < NH_; ++n)
            *(float4*)&smem_big[w][n * H_ + h0] = acc[n];
        if (lane < NH_) smem_big[w][2048 + lane] = sel8(es, lane);
        __syncthreads();

#pragma unroll
        for (int jj = 0; jj < (NH_ * H_) / 256; ++jj) {
            int j = jj * 256 + tid;
            ast(psum + (size_t)bid * (NH_ * H_) + j,
                smem_big[0][j] + smem_big[1][j] + smem_big[2][j] + smem_big[3][j]);
        }
        if (tid < NH_)
            ast(esum_blk + bid * NH_ + tid,
                smem_big[0][2048 + tid] + smem_big[1][2048 + tid]
              + smem_big[2][2048 + tid] + smem_big[3][2048 + tid]);
    }
    gsync(bars + 1 * BAR_STRIDE_, bid);

    // ---- B: per-b ybar reduce + wv + wo + residual (8 blocks) ----
    if (bid < B_) {
        int b = bid;
        float* sinv = smem_big[1];   // [8]
        float* so   = smem_big[2];   // [256]
        float* y0l  = smem_big[3];   // [256]
        y0l[tid] = emb[2 * H_ + tid] + ((tid & 1) ? 1.0f : 0.0f);
        if (tid < 64) {
#pragma unroll
            for (int n = 0; n < NH_; ++n) {
                float v = ald(esum_blk + (b * NCH_ + tid) * NH_ + n);
#pragma unroll
                for (int off = 32; off > 0; off >>= 1) v += __shfl_xor(v, off, 64);
                if (tid == 0) sinv[n] = 1.0f / v;
            }
        }
        __syncthreads();
#pragma unroll
        for (int n = 0; n < NH_; ++n) {
            const float* pp = psum + ((size_t)(b * NCH_) * NH_ + n) * H_ + tid;
            float s = 0.f;
#pragma unroll 8
            for (int cc = 0; cc < NCH_; ++cc) s += ald(pp + (size_t)cc * NH_ * H_);
            smem_q[n * H_ + tid] = s * sinv[n];
        }
        __syncthreads();
        {   // wv projection: tid = n*32+k
            int n = tid >> 5;
            const float* wrow = wv + (size_t)tid * H_;
            const float* yy = smem_q + n * H_;
            float s = 0.f;
#pragma unroll 16
            for (int j4 = 0; j4 < H_ / 4; ++j4) {
                float4 w4 = *(const float4*)(wrow + j4 * 4);
                s += w4.x * yy[j4 * 4] + w4.y * yy[j4 * 4 + 1]
                   + w4.z * yy[j4 * 4 + 2] + w4.w * yy[j4 * 4 + 3];
            }
            so[tid] = s;
        }
        __syncthreads();
        {   // wo projection + double residual
            const float* wrow = wo + (size_t)tid * (NH_ * HD_);
            float s = 0.f;
#pragma unroll 16
            for (int j4 = 0; j4 < (NH_ * HD_) / 4; ++j4) {
                float4 w4 = *(const float4*)(wrow + j4 * 4);
                s += w4.x * so[j4 * 4] + w4.y * so[j4 * 4 + 1]
                   + w4.z * so[j4 * 4 + 2] + w4.w * so[j4 * 4 + 3];
            }
            ast(z + b * H_ + tid, s + 2.0f * y0l[tid]);
        }
    }
    gsync(bars + 2 * BAR_STRIDE_, bid);

    // ---- C: out = z · wu^T (501 blocks) ----
    if (bid < (V_ + 63) / 64) {
        int lane = tid & 63, w = tid >> 6;
        int m = lane & 15;
        int g = lane >> 4;
        int hb = m * 16;
        float* sm_out = smem_big[0];  // [8*65]
        float zr[B_][16];
#pragma unroll
        for (int b = 0; b < B_; ++b)
#pragma unroll
            for (int j = 0; j < 16; ++j)
                zr[b][j] = ald(z + b * H_ + hb + j);

        int base = bid * 64;
#pragma unroll
        for (int pass = 0; pass < 4; ++pass) {
            int rl = w * 16 + pass * 4 + g;
            int v = base + rl;
            int vc = (v < V_) ? v : (V_ - 1);
            const float* wr = wu + (size_t)vc * H_ + hb;
            float4 w0 = *(const float4*)(wr);
            float4 w1 = *(const float4*)(wr + 4);
            float4 w2 = *(const float4*)(wr + 8);
            float4 w3 = *(const float4*)(wr + 12);
            float acc[B_];
#pragma unroll
            for (int b = 0; b < B_; ++b) {
                acc[b] = zr[b][0] * w0.x + zr[b][1] * w0.y + zr[b][2] * w0.z + zr[b][3] * w0.w
                       + zr[b][4] * w1.x + zr[b][5] * w1.y + zr[b][6] * w1.z + zr[b][7] * w1.w
                       + zr[b][8] * w2.x + zr[b][9] * w2.y + zr[b][10] * w2.z + zr[b][11] * w2.w
                       + zr[b][12] * w3.x + zr[b][13] * w3.y + zr[b][14] * w3.z + zr[b][15] * w3.w;
            }
#pragma unroll
            for (int off = 1; off <= 8; off <<= 1) {
#pragma unroll
                for (int b = 0; b < B_; ++b) acc[b] += __shfl_xor(acc[b], off, 64);
            }
            if (m < B_) sm_out[m * 65 + rl] = sel8(acc, m);
        }
        __syncthreads();
        for (int i = tid; i < B_ * 64; i += 256) {
            int b = i >> 6, vl = i & 63, v = base + vl;
            if (v < V_) out[b * V_ + v] = sm_out[b * 65 + vl];
        }
    }
}

// ---------------------------------------------------------------------------
extern "C" void kernel_launch(void* const* d_in, const int* in_sizes, int n_in,
                              void* d_out, int out_size, void* d_ws, size_t ws_size,
                              hipStream_t stream) {
    const int*   x   = (const int*)d_in[0];
    const float* emb = (const float*)d_in[1];
    const float* wq  = (const float*)d_in[2];
    const float* wk  = (const float*)d_in[3];
    const float* wv  = (const float*)d_in[4];
    const float* wo  = (const float*)d_in[5];
    const float* wu  = (const float*)d_in[6];
    float*       out = (float*)d_out;

    // ws layout (floats unless noted), ~4.2 MiB total:
    // qk[2048] | z[2048] | esum_blk[4096] | psum[512*2048] | bars[3*2048 u32]
    float* qk       = (float*)d_ws;
    float* z        = qk + NH_ * H_;
    float* esum_blk = z + B_ * H_;
    float* psum     = esum_blk + 512 * NH_;
    unsigned int* bars = (unsigned int*)(psum + (size_t)512 * NH_ * H_);

    // Zero the barrier counters (workspace is poisoned each iteration).
    hipMemsetAsync(bars, 0, 3 * BAR_STRIDE_ * sizeof(unsigned int), stream);

    mega<<<GRID_, 256, 0, stream>>>(x, emb, wq, wk, wv, wo, wu, out,
                                    qk, z, esum_blk, psum, bars);
}

// Round 6
// 146.926 us; speedup vs baseline: 1.7811x; 1.3643x over previous
//
#include <hip/hip_runtime.h>
#include <stdint.h>

// Problem constants
#define B_   8
#define S_   2047
#define L_   2048      // S+1 (CLS prepended)
#define H_   256       // HIDDEN
#define NH_  8
#define HD_  32
#define V_   32001     // VOCAB+1
#define NCH_ 128       // t-chunks per b
#define TCH_ 16        // t per chunk (NCH_*TCH_ == L_)
#define GRID_ 1024     // 4 blocks/CU x 256 CU -> co-resident
#define BAR_STRIDE_ 2048   // u32 per barrier region (8 KB)

// ---------------------------------------------------------------------------
// LLC-direct (coherent) scalar access: relaxed agent-scope atomics compile to
// global_load/store with sc0 sc1 on gfx950 -> bypass L1 + XCD-L2, hit LLC.
// Proven correct rounds 4-5 (fence-free cross-XCD data passing).
// ---------------------------------------------------------------------------
__device__ __forceinline__ void ast(float* p, float v) {
    __hip_atomic_store((unsigned int*)p, __float_as_uint(v),
                       __ATOMIC_RELAXED, __HIP_MEMORY_SCOPE_AGENT);
}
__device__ __forceinline__ float ald(const float* p) {
    return __uint_as_float(__hip_atomic_load((const unsigned int*)p,
                           __ATOMIC_RELAXED, __HIP_MEMORY_SCOPE_AGENT));
}
__device__ __forceinline__ float foldx(float a, int off) {
    return a + __shfl_xor(a, off, 64);
}
__device__ __forceinline__ float sel8(const float a[8], int j) {
    float v = a[0];
    v = (j == 1) ? a[1] : v;
    v = (j == 2) ? a[2] : v;
    v = (j == 3) ? a[3] : v;
    v = (j == 4) ? a[4] : v;
    v = (j == 5) ? a[5] : v;
    v = (j == 6) ? a[6] : v;
    v = (j == 7) ? a[7] : v;
    return v;
}

// ---------------------------------------------------------------------------
// Software grid barrier, fence-free (round-5 design, scaled to 1024 blocks):
// 32 subgroups x 32 blocks. Arrival: sub counter -> master; release: 32
// separate flag lines, each polled by 32 block-leaders with s_sleep.
// Layout per region (u32): [0]=master | [16+i*16]=sub_i | [528+i*16]=rel_i.
// ---------------------------------------------------------------------------
__device__ __forceinline__ void gsync(unsigned int* bp, int bid) {
    __syncthreads();
    if (threadIdx.x == 0) {
        int sg = bid & 31;
        unsigned int* sub = bp + 16 + sg * 16;
        unsigned int* rel = bp + 528 + sg * 16;
        unsigned int prev = __hip_atomic_fetch_add(sub, 1u, __ATOMIC_RELAXED,
                                                   __HIP_MEMORY_SCOPE_AGENT);
        if (prev == 31u) {
            unsigned int m = __hip_atomic_fetch_add(bp, 1u, __ATOMIC_RELAXED,
                                                    __HIP_MEMORY_SCOPE_AGENT);
            if (m == 31u) {
                for (int i = 0; i < 32; ++i)
                    __hip_atomic_store(bp + 528 + i * 16, 1u, __ATOMIC_RELAXED,
                                       __HIP_MEMORY_SCOPE_AGENT);
            }
        }
        while (__hip_atomic_load(rel, __ATOMIC_RELAXED,
                                 __HIP_MEMORY_SCOPE_AGENT) == 0u)
            __builtin_amdgcn_s_sleep(2);
    }
    __syncthreads();
}

// ---------------------------------------------------------------------------
// Mega kernel, 5 phases, 4 barriers, 1024 blocks (4/CU -> 16 waves/CU):
//   P0 (blocks 0..7):   qk[n][h] = (wq_n y0)·wk_n / sqrt(32)       -> qk
//   A  (all 1024):      fused scores+ybar, 16-t chunk, 4 t/wave    -> psum,esum
//   B1 (blocks 0..63):  per (b,n): 128-chunk reduce -> ybar -> wv  -> o_g
//   B2 (blocks 0..7):   z = wo·o + 2*y0                            -> z
//   C  (blocks 0..500): out[b,v] = z·wu[v] (z staged in padded LDS)
// LDS 32.9 KB, VGPR <= 128 (launch_bounds) -> 4 blocks/CU co-resident.
// ---------------------------------------------------------------------------
__global__ __launch_bounds__(256, 4) void mega(const int* __restrict__ x,
                                               const float* __restrict__ emb,
                                               const float* __restrict__ wq,
                                               const float* __restrict__ wk,
                                               const float* __restrict__ wv,
                                               const float* __restrict__ wo,
                                               const float* __restrict__ wu,
                                               float* __restrict__ out,
                                               float* __restrict__ qk,
                                               float* __restrict__ z,
                                               float* __restrict__ o_g,
                                               float* __restrict__ esum_blk,
                                               float* __restrict__ psum,
                                               unsigned int* __restrict__ bars) {
    int bid = blockIdx.x, tid = threadIdx.x;

    __shared__ float smem[4][2056];          // 32.9 KB, phase-aliased
    float* smf = &smem[0][0];                // flat view

    // ---- P0: qk prep (8 blocks) ----
    if (bid < NH_) {
        int n = bid;
        float* y0l = smem[0];
        float* q0p = smem[1];   // [k*8+part]
        float* q0l = smem[2];
        float v = emb[2 * H_ + tid] + ((tid & 1) ? 1.0f : 0.0f);  // pe[0]
        y0l[tid] = v;
        __syncthreads();
        {
            int k = tid >> 3, part = tid & 7;
            const float* w = wq + (n * HD_ + k) * H_ + part * 32;
            const float* yy = y0l + part * 32;
            float acc = 0.f;
#pragma unroll
            for (int j = 0; j < 32; ++j) acc += w[j] * yy[j];
            q0p[k * 8 + part] = acc;
        }
        __syncthreads();
        if (tid < HD_) {
            float s = 0.f;
#pragma unroll
            for (int j = 0; j < 8; ++j) s += q0p[tid * 8 + j];
            q0l[tid] = s;
        }
        __syncthreads();
        float acc = 0.f;
        for (int k = 0; k < HD_; ++k)
            acc += q0l[k] * wk[(n * HD_ + k) * H_ + tid];
        ast(qk + n * H_ + tid, acc * 0.17677669529663687f);  // 1/sqrt(32)
    }
    gsync(bars + 0 * BAR_STRIDE_, bid);

    // ---- A: fused scores + ybar psums (1024 blocks, 16-t chunks) ----
    {
        int b = bid >> 7, c = bid & 127;
        int lane = tid & 63, w = tid >> 6;
        int h0 = lane * 4;

        // qk staged in smem[3]; freed (re-used as red[3]) after qr load.
        for (int i = tid; i < NH_ * H_; i += 256)
            smem[3][i] = ald(qk + i);
        __syncthreads();

        float4 qr[NH_];
#pragma unroll
        for (int n = 0; n < NH_; ++n)
            qr[n] = *(const float4*)&smem[3][n * H_ + h0];
        __syncthreads();   // qr in regs; smem[3] now dead -> red[3]

        const float cdiv = 0.07195578414202881f;  // ln(10000)/128
        float div0 = __expf(-(float)(lane * 2) * cdiv);
        float div1 = __expf(-(float)(lane * 2 + 1) * cdiv);

        float4 acc[NH_];
        float es[NH_];
#pragma unroll
        for (int n = 0; n < NH_; ++n) {
            acc[n] = make_float4(0.f, 0.f, 0.f, 0.f);
            es[n] = 0.f;
        }

        int t0 = c * TCH_ + w * 4;
        int toks[4];
#pragma unroll
        for (int i = 0; i < 4; ++i) {
            int t = t0 + i;
            toks[i] = (t == 0) ? 2 : x[b * S_ + t - 1];
        }

#pragma unroll
        for (int i = 0; i < 4; ++i) {
            int t = t0 + i;
            float4 ev = *(const float4*)(emb + (size_t)toks[i] * H_ + h0);
            float a0 = (float)t * div0, a1 = (float)t * div1;
            float4 y4;
            y4.x = ev.x + __sinf(a0); y4.y = ev.y + __cosf(a0);
            y4.z = ev.z + __sinf(a1); y4.w = ev.w + __cosf(a1);

            float a[NH_];
#pragma unroll
            for (int n = 0; n < NH_; ++n)
                a[n] = qr[n].x * y4.x + qr[n].y * y4.y + qr[n].z * y4.z + qr[n].w * y4.w;

            float m4[4];
#pragma unroll
            for (int k = 0; k < 4; ++k) {
                float lo = foldx(a[k], 32), hi = foldx(a[k + 4], 32);
                m4[k] = (lane & 32) ? hi : lo;
            }
            float m2[2];
#pragma unroll
            for (int k = 0; k < 2; ++k) {
                float lo = foldx(m4[k], 16), hi = foldx(m4[k + 2], 16);
                m2[k] = (lane & 16) ? hi : lo;
            }
            float lo = foldx(m2[0], 8), hi = foldx(m2[1], 8);
            float m1 = (lane & 8) ? hi : lo;
            m1 = foldx(m1, 4); m1 = foldx(m1, 2); m1 = foldx(m1, 1);
            float e = __expf(m1);  // lane n*8.. holds head n's score sum

#pragma unroll
            for (int n = 0; n < NH_; ++n) {
                float en = __shfl(e, n * 8, 64);
                acc[n].x += en * y4.x; acc[n].y += en * y4.y;
                acc[n].z += en * y4.z; acc[n].w += en * y4.w;
                es[n] += en;
            }
        }

#pragma unroll
        for (int n = 0; n < NH_; ++n)
            *(float4*)&smem[w][n * H_ + h0] = acc[n];
        if (lane < NH_) smem[w][2048 + lane] = sel8(es, lane);
        __syncthreads();

#pragma unroll
        for (int jj = 0; jj < (NH_ * H_) / 256; ++jj) {
            int j = jj * 256 + tid;
            ast(psum + (size_t)bid * (NH_ * H_) + j,
                smem[0][j] + smem[1][j] + smem[2][j] + smem[3][j]);
        }
        if (tid < NH_)
            ast(esum_blk + bid * NH_ + tid,
                smem[0][2048 + tid] + smem[1][2048 + tid]
              + smem[2][2048 + tid] + smem[3][2048 + tid]);
    }
    gsync(bars + 1 * BAR_STRIDE_, bid);

    // ---- B1: per-(b,n) chunk reduce -> ybar -> wv -> o_g (64 blocks) ----
    if (bid < 64) {
        int b = bid >> 3, n = bid & 7;
        float* ybar  = smem[0];          // [256]
        float* opb   = smem[1];          // [256] = op[k*8+p]
        float* es128 = smem[2];          // [128], sinv at [192]
        if (tid < 128)
            es128[tid] = ald(esum_blk + (size_t)(b * NCH_ + tid) * NH_ + n);
        __syncthreads();
        if (tid < 64) {
            float v = es128[tid] + es128[tid + 64];
#pragma unroll
            for (int off = 32; off > 0; off >>= 1) v += __shfl_xor(v, off, 64);
            if (tid == 0) es128[192] = 1.0f / v;
        }
        __syncthreads();
        {
            const float* pp = psum + (size_t)(b * NCH_) * (NH_ * H_) + n * H_ + tid;
            float s = 0.f;
#pragma unroll 16
            for (int cc = 0; cc < NCH_; ++cc) s += ald(pp + (size_t)cc * NH_ * H_);
            ybar[tid] = s * es128[192];
        }
        __syncthreads();
        {   // wv projection: tid = (k, p)
            int k = tid >> 3, p = tid & 7;
            const float* wrow = wv + (size_t)(n * HD_ + k) * H_ + p * 32;
            const float* yy = ybar + p * 32;
            float s = 0.f;
#pragma unroll
            for (int j = 0; j < 32; ++j) s += wrow[j] * yy[j];
            opb[k * 8 + p] = s;
        }
        __syncthreads();
        if (tid < HD_) {
            float s = 0.f;
#pragma unroll
            for (int p = 0; p < 8; ++p) s += opb[tid * 8 + p];
            ast(o_g + b * (NH_ * HD_) + n * HD_ + tid, s);
        }
    }
    gsync(bars + 2 * BAR_STRIDE_, bid);

    // ---- B2: z = wo·o + 2*y0 (8 blocks) ----
    if (bid < B_) {
        int b = bid;
        float* o_l = smem[0];
        o_l[tid] = ald(o_g + b * (NH_ * HD_) + tid);
        float y0v = emb[2 * H_ + tid] + ((tid & 1) ? 1.0f : 0.0f);
        __syncthreads();
        const float* wrow = wo + (size_t)tid * (NH_ * HD_);
        float s = 0.f;
#pragma unroll 16
        for (int j4 = 0; j4 < (NH_ * HD_) / 4; ++j4) {
            float4 w4 = *(const float4*)(wrow + j4 * 4);
            s += w4.x * o_l[j4 * 4] + w4.y * o_l[j4 * 4 + 1]
               + w4.z * o_l[j4 * 4 + 2] + w4.w * o_l[j4 * 4 + 3];
        }
        ast(z + b * H_ + tid, s + 2.0f * y0v);
    }
    gsync(bars + 3 * BAR_STRIDE_, bid);

    // ---- C: out = z · wu^T (501 blocks, z staged in padded LDS) ----
    if (bid < (V_ + 63) / 64) {
        int lane = tid & 63, w = tid >> 6;
        int m = lane & 15;
        int g = lane >> 4;
        // zs[b*320 + (h>>4)*20 + (h&15)]: stride-20 pad -> 2-way bank alias
        // (free), 16B-aligned float4 reads. 2560 floats.
        float* zs = smf;
        float* sm_out = smf + 2560;      // [8*65]
        for (int i = tid; i < B_ * H_; i += 256) {
            int b = i >> 8, h = i & 255;
            zs[b * 320 + (h >> 4) * 20 + (h & 15)] = ald(z + i);
        }
        __syncthreads();

        int base = bid * 64;
#pragma unroll
        for (int pass = 0; pass < 4; ++pass) {
            int rl = w * 16 + pass * 4 + g;
            int v = base + rl;
            int vc = (v < V_) ? v : (V_ - 1);
            const float* wr = wu + (size_t)vc * H_ + m * 16;
            float4 w0 = *(const float4*)(wr);
            float4 w1 = *(const float4*)(wr + 4);
            float4 w2 = *(const float4*)(wr + 8);
            float4 w3 = *(const float4*)(wr + 12);
            float acc[B_];
#pragma unroll
            for (int b = 0; b < B_; ++b) {
                const float* zb = zs + b * 320 + m * 20;
                float4 z0 = *(const float4*)(zb);
                float4 z1 = *(const float4*)(zb + 4);
                float4 z2 = *(const float4*)(zb + 8);
                float4 z3 = *(const float4*)(zb + 12);
                acc[b] = z0.x * w0.x + z0.y * w0.y + z0.z * w0.z + z0.w * w0.w
                       + z1.x * w1.x + z1.y * w1.y + z1.z * w1.z + z1.w * w1.w
                       + z2.x * w2.x + z2.y * w2.y + z2.z * w2.z + z2.w * w2.w
                       + z3.x * w3.x + z3.y * w3.y + z3.z * w3.z + z3.w * w3.w;
            }
#pragma unroll
            for (int off = 1; off <= 8; off <<= 1) {
#pragma unroll
                for (int b = 0; b < B_; ++b) acc[b] += __shfl_xor(acc[b], off, 64);
            }
            if (m < B_) sm_out[m * 65 + rl] = sel8(acc, m);
        }
        __syncthreads();
        for (int i = tid; i < B_ * 64; i += 256) {
            int b = i >> 6, vl = i & 63, v = base + vl;
            if (v < V_) out[b * V_ + v] = sm_out[b * 65 + vl];
        }
    }
}

// ---------------------------------------------------------------------------
extern "C" void kernel_launch(void* const* d_in, const int* in_sizes, int n_in,
                              void* d_out, int out_size, void* d_ws, size_t ws_size,
                              hipStream_t stream) {
    const int*   x   = (const int*)d_in[0];
    const float* emb = (const float*)d_in[1];
    const float* wq  = (const float*)d_in[2];
    const float* wk  = (const float*)d_in[3];
    const float* wv  = (const float*)d_in[4];
    const float* wo  = (const float*)d_in[5];
    const float* wu  = (const float*)d_in[6];
    float*       out = (float*)d_out;

    // ws layout (floats unless noted), ~8.2 MiB total:
    // qk[2048] | z[2048] | o_g[2048] | esum_blk[8192] | psum[1024*2048]
    // | bars[4*2048 u32]
    float* qk       = (float*)d_ws;
    float* z        = qk + NH_ * H_;
    float* o_g      = z + B_ * H_;
    float* esum_blk = o_g + B_ * NH_ * HD_;
    float* psum     = esum_blk + GRID_ * NH_;
    unsigned int* bars = (unsigned int*)(psum + (size_t)GRID_ * NH_ * H_);

    // Zero the barrier counters (workspace is poisoned each iteration).
    hipMemsetAsync(bars, 0, 4 * BAR_STRIDE_ * sizeof(unsigned int), stream);

    mega<<<GRID_, 256, 0, stream>>>(x, emb, wq, wk, wv, wo, wu, out,
                                    qk, z, o_g, esum_blk, psum, bars);
}